// Round 11
// baseline (186.203 us; speedup 1.0000x reference)
//
#include <hip/hip_runtime.h>
#include <math.h>

#define BS 16
#define C 64
#define H 128
#define W 128
#define HW (H*W)
#define NC 80
#define TOPK 128
#define KALL (TOPK+NC)
#define TAU 0.07f
#define EPSN 1e-12f
#define OUT_N 20971521          // 1 + BS*NC*HW
#define ZBLK 1280               // zero-fill blocks (1024 thr, 4 float4 each)
#define GBLK (BS*KALL/4)        // 832 gather blocks (4 waves each)
#define LOSSBLK (BS*NC)         // 1280

// ---------------- fused: zero the output + find hm==1.0 peak per (b,n) ----------------
__global__ __launch_bounds__(1024) void k_peak_zero(const float* __restrict__ hm,
                                                    int* __restrict__ peak_pos,
                                                    float* __restrict__ out) {
    int t = threadIdx.x;
    if (blockIdx.x >= BS * NC) {
        // ---- zero-fill portion: covers float4 [0, 5242880) = out[0..20971520) ----
        int zb = blockIdx.x - BS * NC;
        float4* o4 = (float4*)out;
        float4 z = make_float4(0.f, 0.f, 0.f, 0.f);
        int idx = zb * 1024 + t;
        #pragma unroll
        for (int j = 0; j < 4; ++j) o4[idx + j * (ZBLK * 1024)] = z;
        if (zb == 0 && t == 0) out[OUT_N - 1] = 0.0f;   // tail element
        return;
    }
    __shared__ int wmax[16];
    int bn = blockIdx.x;
    int lane = t & 63, wid = t >> 6;
    const float4* p = (const float4*)(hm + (size_t)bn * HW);
    int found = -1;
    #pragma unroll
    for (int j = 0; j < 4; ++j) {
        int gi = j * 1024 + t;            // contiguous across lanes
        float4 v = p[gi];
        int base = gi * 4;
        if (v.x == 1.0f) found = base;
        if (v.y == 1.0f) found = base + 1;
        if (v.z == 1.0f) found = base + 2;
        if (v.w == 1.0f) found = base + 3;
    }
    #pragma unroll
    for (int off = 1; off < 64; off <<= 1) found = max(found, __shfl_xor(found, off));
    if (lane == 0) wmax[wid] = found;
    __syncthreads();
    if (t == 0) {
        int m = wmax[0];
        #pragma unroll
        for (int i = 1; i < 16; ++i) m = max(m, wmax[i]);
        peak_pos[bn] = m;                 // at most one peak per (b,n)
    }
}

// ---------------- per-pixel masked max/argmax over classes (4 px/thread) ----------------
__global__ void k_max(const float* __restrict__ score, const int* __restrict__ peak_pos,
                      float* __restrict__ maxv, int* __restrict__ clsidx) {
    __shared__ int pk[NC];
    int b = blockIdx.y;
    int g = blockIdx.x * blockDim.x + threadIdx.x;   // float4 group 0..4095
    if (threadIdx.x < NC) pk[threadIdx.x] = peak_pos[b * NC + threadIdx.x];
    __syncthreads();
    const float4* sb = (const float4*)(score + (size_t)b * NC * HW);
    int p0 = g * 4;
    int pp0 = pk[0];
    float m0 = (pp0 >= 0) ? 1.0f : 0.0f;
    float4 v0 = sb[g];
    float bx = v0.x * m0, by = v0.y * m0, bz = v0.z * m0, bw = v0.w * m0;
    int ix = 0, iy = 0, iz = 0, iw = 0;
    bool pe0 = (pp0 == p0), pe1 = (pp0 == p0 + 1), pe2 = (pp0 == p0 + 2), pe3 = (pp0 == p0 + 3);
    #pragma unroll 8
    for (int n = 1; n < NC; ++n) {
        int pp = pk[n];
        float m = (pp >= 0) ? 1.0f : 0.0f;
        float4 v = sb[(size_t)n * (HW / 4) + g];
        float vx = v.x * m, vy = v.y * m, vz = v.z * m, vw = v.w * m;
        if (vx > bx) { bx = vx; ix = n; }
        if (vy > by) { by = vy; iy = n; }
        if (vz > bz) { bz = vz; iz = n; }
        if (vw > bw) { bw = vw; iw = n; }
        pe0 |= (pp == p0); pe1 |= (pp == p0 + 1); pe2 |= (pp == p0 + 2); pe3 |= (pp == p0 + 3);
    }
    if (pe0) { bx = 0.0f; ix = 0; }
    if (pe1) { by = 0.0f; iy = 0; }
    if (pe2) { bz = 0.0f; iz = 0; }
    if (pe3) { bw = 0.0f; iw = 0; }
    ((float4*)maxv)[(size_t)b * (HW / 4) + g] = make_float4(bx, by, bz, bw);
    ((int4*)clsidx)[(size_t)b * (HW / 4) + g] = make_int4(ix, iy, iz, iw);
}

// ---------------- exact top-128 per batch via 3-round radix select ----------------
__global__ __launch_bounds__(1024) void k_topk(const float* __restrict__ maxv,
                                               const int* __restrict__ clsidx,
                                               float* __restrict__ topkv,
                                               int* __restrict__ topki,
                                               int* __restrict__ topkc,
                                               int* __restrict__ counter) {
    __shared__ unsigned int hist[2048];
    __shared__ unsigned int wtot[16];
    __shared__ unsigned int woff[16];
    __shared__ unsigned int s_pref;
    __shared__ int s_rank;
    __shared__ unsigned int s_bin;
    __shared__ unsigned int s_above;

    int b = blockIdx.x, t = threadIdx.x;
    int lane = t & 63, wid = t >> 6;
    if (b == 0 && t == 0) *counter = 0;              // reset for k_loss_final

    unsigned int key[16];
    const float4* mv4 = (const float4*)(maxv + (size_t)b * HW);
    #pragma unroll
    for (int j4 = 0; j4 < 4; ++j4) {
        float4 v = mv4[t * 4 + j4];
        key[j4 * 4 + 0] = __float_as_uint(v.x);
        key[j4 * 4 + 1] = __float_as_uint(v.y);
        key[j4 * 4 + 2] = __float_as_uint(v.z);
        key[j4 * 4 + 3] = __float_as_uint(v.w);
    }

    if (t == 0) { s_pref = 0u; s_rank = TOPK; }

    const int shifts[3] = {21, 10, 0};
    const int widths[3] = {11, 11, 10};

    for (int rnd = 0; rnd < 3; ++rnd) {
        int sh = shifts[rnd], w = widths[rnd];
        unsigned mask = (1u << w) - 1u;
        hist[t] = 0u; hist[t + 1024] = 0u;
        __syncthreads();
        unsigned pref = s_pref;
        int hiShift = sh + w;
        #pragma unroll
        for (int j = 0; j < 16; ++j) {
            unsigned k = key[j];
            bool ok = (rnd == 0) || ((k >> hiShift) == pref);
            if (ok) atomicAdd(&hist[(k >> sh) & mask], 1u);
        }
        __syncthreads();
        unsigned p = hist[2 * t] + hist[2 * t + 1];
        unsigned s = p;
        #pragma unroll
        for (int off = 1; off < 64; off <<= 1) {
            unsigned o = __shfl_down(s, off);
            if (lane + off < 64) s += o;
        }
        if (lane == 0) wtot[wid] = s;
        __syncthreads();
        if (wid == 0) {
            unsigned vv = (lane < 16) ? wtot[lane] : 0u;
            unsigned ss = vv;
            #pragma unroll
            for (int off = 1; off < 64; off <<= 1) {
                unsigned o = __shfl_down(ss, off);
                if (lane + off < 64) ss += o;
            }
            if (lane < 16) woff[lane] = ss - vv;
        }
        __syncthreads();
        unsigned S_t = s + woff[wid];
        unsigned S_next = S_t - p;
        int r = s_rank;
        if ((int)S_t >= r && (int)S_next < r) {
            unsigned hi = hist[2 * t + 1];
            if ((int)(S_next + hi) >= r) { s_bin = 2u * t + 1u; s_above = S_next; }
            else                         { s_bin = 2u * t;      s_above = S_next + hi; }
        }
        __syncthreads();
        if (t == 0) {
            s_pref = (s_pref << w) | s_bin;
            s_rank = s_rank - (int)s_above;
        }
        __syncthreads();
    }
    unsigned K = s_pref;
    int need_eq = s_rank;
    int cnt_gt = TOPK - need_eq;

    int cg = 0, ce = 0;
    #pragma unroll
    for (int j = 0; j < 16; ++j) { cg += (key[j] > K); ce += (key[j] == K); }
    unsigned v = ((unsigned)cg << 16) | (unsigned)ce;
    unsigned sc = v;
    #pragma unroll
    for (int off = 1; off < 64; off <<= 1) {
        unsigned o = __shfl_up(sc, off);
        if (lane >= off) sc += o;
    }
    if (lane == 63) wtot[wid] = sc;
    __syncthreads();
    if (wid == 0) {
        unsigned vv = (lane < 16) ? wtot[lane] : 0u;
        unsigned ss = vv;
        #pragma unroll
        for (int off = 1; off < 64; off <<= 1) {
            unsigned o = __shfl_up(ss, off);
            if (lane >= off) ss += o;
        }
        if (lane < 16) woff[lane] = ss - vv;
    }
    __syncthreads();
    unsigned ex = (sc - v) + woff[wid];
    int pg = (int)(ex >> 16);
    int pe = (int)(ex & 0xffffu);
    int lg = 0, le = 0;
    #pragma unroll
    for (int j = 0; j < 16; ++j) {
        unsigned k = key[j];
        int slot = -1;
        if (k > K) { slot = pg + lg; ++lg; }
        else if (k == K) { int er = pe + le; ++le; if (er < need_eq) slot = cnt_gt + er; }
        if (slot >= 0) {
            int idx = t * 16 + j;
            topkv[b * TOPK + slot] = __uint_as_float(k);
            topki[b * TOPK + slot] = idx;
            topkc[b * TOPK + slot] = clsidx[(size_t)b * HW + idx];
        }
    }
}

// ------- gather/normalize (blocks 0..831) + 0.9 scatter (block 832) -------
__global__ __launch_bounds__(256) void k_gather_sc(const float* __restrict__ feat,
                                                   const int* __restrict__ peak_pos,
                                                   const float* __restrict__ topkv,
                                                   const int* __restrict__ topki,
                                                   const int* __restrict__ topkc,
                                                   float* __restrict__ k_all,
                                                   float* __restrict__ qv,
                                                   float* __restrict__ out) {
    int t = threadIdx.x;
    if (blockIdx.x == GBLK) {
        #pragma unroll
        for (int j = 0; j < 8; ++j) {
            int i = j * 256 + t;                     // [0, 2048)
            if (topkv[i] > 0.0f) {
                int b = i >> 7;
                out[1 + (((size_t)b * NC + topkc[i]) << 14) + topki[i]] = 0.9f;
            }
        }
        return;
    }
    int wid = t >> 6, lane = t & 63;
    int bk = blockIdx.x * 4 + wid;                   // [0, BS*KALL)
    int b = bk / KALL, k = bk % KALL, c = lane;
    int pos;
    if (k < TOPK) {
        pos = topki[b * TOPK + k];
    } else {
        int n = k - TOPK;
        int pp = peak_pos[b * NC + n];
        if (pp < 0) {
            k_all[((size_t)b * KALL + k) * C + c] = 0.0f;
            qv[((size_t)b * NC + n) * C + c] = 0.0f;
            return;
        }
        pos = pp;
    }
    float v = feat[((size_t)b * C + c) * HW + pos];
    float ss = v * v;
    #pragma unroll
    for (int off = 1; off < 64; off <<= 1) ss += __shfl_xor(ss, off);
    float qc = v / fmaxf(sqrtf(ss), EPSN);           // feat_n component
    if (k < TOPK) {
        k_all[((size_t)b * KALL + k) * C + c] = qc;
    } else {
        int n = k - TOPK;
        qv[((size_t)b * NC + n) * C + c] = qc;       // q (single-normalized)
        float qq = qc * qc;                          // k0 = normalize(q)
        #pragma unroll
        for (int off = 1; off < 64; off <<= 1) qq += __shfl_xor(qq, off);
        k_all[((size_t)b * KALL + k) * C + c] = qc / fmaxf(sqrtf(qq), EPSN);
    }
}

// -------- contrastive loss per (b,n) + last-block final reduction --------
__global__ __launch_bounds__(256) void k_loss_final(const float* __restrict__ k_all,
                                                    const float* __restrict__ qv,
                                                    const int* __restrict__ peak_pos,
                                                    const float* __restrict__ topkv,
                                                    const int* __restrict__ topkc,
                                                    float* __restrict__ loss_bn,
                                                    int* __restrict__ counter,
                                                    float* __restrict__ out) {
    __shared__ float qs[C];
    __shared__ float r1[256];
    __shared__ float r2[256];
    __shared__ float s_simsum, s_num;
    __shared__ int s_last;
    int bn = blockIdx.x;
    int b = bn / NC, n = bn % NC, t = threadIdx.x;
    bool present = (peak_pos[bn] >= 0);
    float sim = 0.0f, kam = 0.0f, km = 0.0f;
    if (present) {
        if (t < C) qs[t] = qv[(size_t)bn * C + t];
        __syncthreads();
        if (t < KALL) {
            const float* kr = k_all + ((size_t)b * KALL + t) * C;
            float dot = 0.0f;
            for (int c2 = 0; c2 < C; ++c2) dot += qs[c2] * kr[c2];
            sim = expf(dot / TAU);
            if (t < TOPK) {
                float posm = (topkv[b * TOPK + t] > 0.0f) ? 1.0f : 0.0f;
                kam = posm;
                km = (topkc[b * TOPK + t] == n) ? posm : 0.0f;
            } else {
                int j = t - TOPK;
                kam = (peak_pos[b * NC + j] >= 0) ? 1.0f : 0.0f;
                km = (j == n) ? 1.0f : 0.0f;
            }
        }
        r1[t] = sim * kam;
        r2[t] = km;
        __syncthreads();
        for (int s = 128; s > 0; s >>= 1) {
            if (t < s) { r1[t] += r1[t + s]; r2[t] += r2[t + s]; }
            __syncthreads();
        }
        if (t == 0) {
            float ss = r1[0];
            s_simsum = (ss == 0.0f) ? 1.0f : ss;
            s_num = (r2[0] == 0.0f) ? 1.0f : r2[0];
        }
        __syncthreads();
        r1[t] = (km > 0.0f) ? logf(sim / s_simsum) : 0.0f;
        __syncthreads();
        for (int s = 128; s > 0; s >>= 1) {
            if (t < s) r1[t] += r1[t + s];
            __syncthreads();
        }
        if (t == 0) loss_bn[bn] = r1[0] / s_num;
    } else {
        if (t == 0) loss_bn[bn] = 0.0f;
        __syncthreads();
    }
    // last-finishing block performs the final reduction (no bulk writes here,
    // so the fences are cheap — unlike R5 where they poisoned the 84MB stream)
    __threadfence();
    __syncthreads();
    if (t == 0) s_last = (atomicAdd(counter, 1) == LOSSBLK - 1) ? 1 : 0;
    __syncthreads();
    if (s_last) {
        __threadfence();
        float s = 0.0f, cnt = 0.0f;
        for (int i = t; i < BS * NC; i += 256) {
            s += loss_bn[i];
            cnt += (peak_pos[i] >= 0) ? 1.0f : 0.0f;
        }
        r1[t] = s; r2[t] = cnt;
        __syncthreads();
        for (int st = 128; st > 0; st >>= 1) {
            if (t < st) { r1[t] += r1[t + st]; r2[t] += r2[t + st]; }
            __syncthreads();
        }
        if (t == 0) out[0] = -(r1[0] / r2[0]);
    }
}

extern "C" void kernel_launch(void* const* d_in, const int* in_sizes, int n_in,
                              void* d_out, int out_size, void* d_ws, size_t ws_size,
                              hipStream_t stream) {
    const float* feat  = (const float*)d_in[0];
    const float* score = (const float*)d_in[1];
    const float* hm    = (const float*)d_in[2];
    float* out = (float*)d_out;

    char* ws = (char*)d_ws;
    size_t off = 0;
    auto alloc = [&](size_t bytes) -> void* {
        void* p = ws + off;
        off += (bytes + 255) & ~(size_t)255;
        return p;
    };
    int*   peak_pos = (int*)  alloc((size_t)BS * NC * 4);
    float* maxv     = (float*)alloc((size_t)BS * HW * 4);
    int*   clsidx   = (int*)  alloc((size_t)BS * HW * 4);
    float* topkv    = (float*)alloc((size_t)BS * TOPK * 4);
    int*   topki    = (int*)  alloc((size_t)BS * TOPK * 4);
    int*   topkc    = (int*)  alloc((size_t)BS * TOPK * 4);
    float* k_all    = (float*)alloc((size_t)BS * KALL * C * 4);
    float* qv       = (float*)alloc((size_t)BS * NC * C * 4);
    float* loss_bn  = (float*)alloc((size_t)BS * NC * 4);
    int*   counter  = (int*)  alloc(256);

    k_peak_zero<<<BS * NC + ZBLK, 1024, 0, stream>>>(hm, peak_pos, out);
    dim3 gmax(HW / 4 / 256, BS);
    k_max<<<gmax, 256, 0, stream>>>(score, peak_pos, maxv, clsidx);
    k_topk<<<BS, 1024, 0, stream>>>(maxv, clsidx, topkv, topki, topkc, counter);
    k_gather_sc<<<GBLK + 1, 256, 0, stream>>>(feat, peak_pos, topkv, topki, topkc,
                                              k_all, qv, out);
    k_loss_final<<<LOSSBLK, 256, 0, stream>>>(k_all, qv, peak_pos, topkv, topkc,
                                              loss_bn, counter, out);
}

// Round 12
// 93.471 us; speedup vs baseline: 1.9921x; 1.9921x over previous
//
#include <hip/hip_runtime.h>
#include <math.h>

#define BS 16
#define C 64
#define H 128
#define W 128
#define HW (H*W)
#define NC 80
#define TOPK 128
#define KALL (TOPK+NC)
#define TAU 0.07f
#define EPSN 1e-12f
#define OUT_N 20971521          // 1 + BS*NC*HW
#define ZBLK 1280               // zero-fill blocks (1024 thr, 4 float4 each)

// ---------------- fused: zero the output + find hm==1.0 peak per (b,n) ----------------
__global__ __launch_bounds__(1024) void k_peak_zero(const float* __restrict__ hm,
                                                    int* __restrict__ peak_pos,
                                                    float* __restrict__ out) {
    int t = threadIdx.x;
    if (blockIdx.x >= BS * NC) {
        // ---- zero-fill portion: covers float4 [0, 5242880) = out[0..20971520) ----
        int zb = blockIdx.x - BS * NC;
        float4* o4 = (float4*)out;
        float4 z = make_float4(0.f, 0.f, 0.f, 0.f);
        int idx = zb * 1024 + t;
        #pragma unroll
        for (int j = 0; j < 4; ++j) o4[idx + j * (ZBLK * 1024)] = z;
        if (zb == 0 && t == 0) out[OUT_N - 1] = 0.0f;   // tail element
        return;
    }
    __shared__ int wmax[16];
    int bn = blockIdx.x;
    int lane = t & 63, wid = t >> 6;
    const float4* p = (const float4*)(hm + (size_t)bn * HW);
    int found = -1;
    #pragma unroll
    for (int j = 0; j < 4; ++j) {
        int gi = j * 1024 + t;            // contiguous across lanes
        float4 v = p[gi];
        int base = gi * 4;
        if (v.x == 1.0f) found = base;
        if (v.y == 1.0f) found = base + 1;
        if (v.z == 1.0f) found = base + 2;
        if (v.w == 1.0f) found = base + 3;
    }
    #pragma unroll
    for (int off = 1; off < 64; off <<= 1) found = max(found, __shfl_xor(found, off));
    if (lane == 0) wmax[wid] = found;
    __syncthreads();
    if (t == 0) {
        int m = wmax[0];
        #pragma unroll
        for (int i = 1; i < 16; ++i) m = max(m, wmax[i]);
        peak_pos[bn] = m;                 // at most one peak per (b,n)
    }
}

// ---------------- per-pixel masked max/argmax over classes (4 px/thread) ----------------
__global__ void k_max(const float* __restrict__ score, const int* __restrict__ peak_pos,
                      float* __restrict__ maxv, int* __restrict__ clsidx) {
    __shared__ int pk[NC];
    int b = blockIdx.y;
    int g = blockIdx.x * blockDim.x + threadIdx.x;   // float4 group 0..4095
    if (threadIdx.x < NC) pk[threadIdx.x] = peak_pos[b * NC + threadIdx.x];
    __syncthreads();
    const float4* sb = (const float4*)(score + (size_t)b * NC * HW);
    int p0 = g * 4;
    int pp0 = pk[0];
    float m0 = (pp0 >= 0) ? 1.0f : 0.0f;
    float4 v0 = sb[g];
    float bx = v0.x * m0, by = v0.y * m0, bz = v0.z * m0, bw = v0.w * m0;
    int ix = 0, iy = 0, iz = 0, iw = 0;
    bool pe0 = (pp0 == p0), pe1 = (pp0 == p0 + 1), pe2 = (pp0 == p0 + 2), pe3 = (pp0 == p0 + 3);
    #pragma unroll 8
    for (int n = 1; n < NC; ++n) {
        int pp = pk[n];
        float m = (pp >= 0) ? 1.0f : 0.0f;
        float4 v = sb[(size_t)n * (HW / 4) + g];
        float vx = v.x * m, vy = v.y * m, vz = v.z * m, vw = v.w * m;
        if (vx > bx) { bx = vx; ix = n; }
        if (vy > by) { by = vy; iy = n; }
        if (vz > bz) { bz = vz; iz = n; }
        if (vw > bw) { bw = vw; iw = n; }
        pe0 |= (pp == p0); pe1 |= (pp == p0 + 1); pe2 |= (pp == p0 + 2); pe3 |= (pp == p0 + 3);
    }
    // GT-peak pixels: score*0 -> max 0, argmax 0 (first class)
    if (pe0) { bx = 0.0f; ix = 0; }
    if (pe1) { by = 0.0f; iy = 0; }
    if (pe2) { bz = 0.0f; iz = 0; }
    if (pe3) { bw = 0.0f; iw = 0; }
    ((float4*)maxv)[(size_t)b * (HW / 4) + g] = make_float4(bx, by, bz, bw);
    ((int4*)clsidx)[(size_t)b * (HW / 4) + g] = make_int4(ix, iy, iz, iw);
}

// ---------------- exact top-128 per batch via 3-round radix select ----------------
// maxv >= 0 so float bit pattern is order-monotonic as uint32.
__global__ __launch_bounds__(1024) void k_topk(const float* __restrict__ maxv,
                                               const int* __restrict__ clsidx,
                                               float* __restrict__ topkv,
                                               int* __restrict__ topki,
                                               int* __restrict__ topkc) {
    __shared__ unsigned int hist[2048];
    __shared__ unsigned int wtot[16];
    __shared__ unsigned int woff[16];
    __shared__ unsigned int s_pref;
    __shared__ int s_rank;
    __shared__ unsigned int s_bin;
    __shared__ unsigned int s_above;

    int b = blockIdx.x, t = threadIdx.x;
    int lane = t & 63, wid = t >> 6;
    unsigned int key[16];
    const float4* mv4 = (const float4*)(maxv + (size_t)b * HW);
    #pragma unroll
    for (int j4 = 0; j4 < 4; ++j4) {
        float4 v = mv4[t * 4 + j4];
        key[j4 * 4 + 0] = __float_as_uint(v.x);
        key[j4 * 4 + 1] = __float_as_uint(v.y);
        key[j4 * 4 + 2] = __float_as_uint(v.z);
        key[j4 * 4 + 3] = __float_as_uint(v.w);
    }

    if (t == 0) { s_pref = 0u; s_rank = TOPK; }

    const int shifts[3] = {21, 10, 0};
    const int widths[3] = {11, 11, 10};

    for (int rnd = 0; rnd < 3; ++rnd) {
        int sh = shifts[rnd], w = widths[rnd];
        unsigned mask = (1u << w) - 1u;
        hist[t] = 0u; hist[t + 1024] = 0u;
        __syncthreads();
        unsigned pref = s_pref;
        int hiShift = sh + w;
        #pragma unroll
        for (int j = 0; j < 16; ++j) {
            unsigned k = key[j];
            bool ok = (rnd == 0) || ((k >> hiShift) == pref);
            if (ok) atomicAdd(&hist[(k >> sh) & mask], 1u);
        }
        __syncthreads();
        // suffix scan over 2048 bins, as 1024 pairs
        unsigned p = hist[2 * t] + hist[2 * t + 1];
        unsigned s = p;
        #pragma unroll
        for (int off = 1; off < 64; off <<= 1) {
            unsigned o = __shfl_down(s, off);
            if (lane + off < 64) s += o;
        }
        if (lane == 0) wtot[wid] = s;
        __syncthreads();
        if (wid == 0) {
            unsigned vv = (lane < 16) ? wtot[lane] : 0u;
            unsigned ss = vv;
            #pragma unroll
            for (int off = 1; off < 64; off <<= 1) {
                unsigned o = __shfl_down(ss, off);
                if (lane + off < 64) ss += o;
            }
            if (lane < 16) woff[lane] = ss - vv;   // sum of waves strictly after
        }
        __syncthreads();
        unsigned S_t = s + woff[wid];      // count in pairs [t..1023]
        unsigned S_next = S_t - p;         // count in pairs (t..1023]
        int r = s_rank;
        if ((int)S_t >= r && (int)S_next < r) {    // unique crossing pair
            unsigned hi = hist[2 * t + 1];
            if ((int)(S_next + hi) >= r) { s_bin = 2u * t + 1u; s_above = S_next; }
            else                         { s_bin = 2u * t;      s_above = S_next + hi; }
        }
        __syncthreads();
        if (t == 0) {
            s_pref = (s_pref << w) | s_bin;
            s_rank = s_rank - (int)s_above;
        }
        __syncthreads();
    }
    unsigned K = s_pref;          // exact 128th-largest key
    int need_eq = s_rank;         // how many ==K to take (lowest indices)
    int cnt_gt = TOPK - need_eq;

    // deterministic slots via block prefix scan of (count_gt, count_eq)
    int cg = 0, ce = 0;
    #pragma unroll
    for (int j = 0; j < 16; ++j) { cg += (key[j] > K); ce += (key[j] == K); }
    unsigned v = ((unsigned)cg << 16) | (unsigned)ce;
    unsigned sc = v;
    #pragma unroll
    for (int off = 1; off < 64; off <<= 1) {
        unsigned o = __shfl_up(sc, off);
        if (lane >= off) sc += o;
    }
    if (lane == 63) wtot[wid] = sc;
    __syncthreads();
    if (wid == 0) {
        unsigned vv = (lane < 16) ? wtot[lane] : 0u;
        unsigned ss = vv;
        #pragma unroll
        for (int off = 1; off < 64; off <<= 1) {
            unsigned o = __shfl_up(ss, off);
            if (lane >= off) ss += o;
        }
        if (lane < 16) woff[lane] = ss - vv;   // exclusive wave prefix
    }
    __syncthreads();
    unsigned ex = (sc - v) + woff[wid];        // exclusive prefix for this thread
    int pg = (int)(ex >> 16);
    int pe = (int)(ex & 0xffffu);
    int lg = 0, le = 0;
    #pragma unroll
    for (int j = 0; j < 16; ++j) {
        unsigned k = key[j];
        int slot = -1;
        if (k > K) { slot = pg + lg; ++lg; }
        else if (k == K) { int er = pe + le; ++le; if (er < need_eq) slot = cnt_gt + er; }
        if (slot >= 0) {
            int idx = t * 16 + j;
            topkv[b * TOPK + slot] = __uint_as_float(k);
            topki[b * TOPK + slot] = idx;
            topkc[b * TOPK + slot] = clsidx[(size_t)b * HW + idx];
        }
    }
}

// ---------------- gather & normalize feat at topk + peak positions ----------------
__global__ void k_gather(const float* __restrict__ feat, const int* __restrict__ peak_pos,
                         const int* __restrict__ topki, float* k_all, float* qv) {
    int bk = blockIdx.x;
    int b = bk / KALL, k = bk % KALL, c = threadIdx.x;
    int pos;
    if (k < TOPK) {
        pos = topki[b * TOPK + k];
    } else {
        int n = k - TOPK;
        int pp = peak_pos[b * NC + n];
        if (pp < 0) {
            k_all[((size_t)b * KALL + k) * C + c] = 0.0f;
            qv[((size_t)b * NC + n) * C + c] = 0.0f;
            return;
        }
        pos = pp;
    }
    float v = feat[((size_t)b * C + c) * HW + pos];
    float ss = v * v;
    #pragma unroll
    for (int off = 1; off < 64; off <<= 1) ss += __shfl_xor(ss, off);
    float qc = v / fmaxf(sqrtf(ss), EPSN);       // feat_n component
    if (k < TOPK) {
        k_all[((size_t)b * KALL + k) * C + c] = qc;
    } else {
        int n = k - TOPK;
        qv[((size_t)b * NC + n) * C + c] = qc;   // q (single-normalized)
        float qq = qc * qc;                      // k0 = normalize(q)
        #pragma unroll
        for (int off = 1; off < 64; off <<= 1) qq += __shfl_xor(qq, off);
        k_all[((size_t)b * KALL + k) * C + c] = qc / fmaxf(sqrtf(qq), EPSN);
    }
}

// ---------------- contrastive loss per (b,n) — fence-free ----------------
__global__ __launch_bounds__(256) void k_loss(const float* __restrict__ k_all,
                                              const float* __restrict__ qv,
                                              const int* __restrict__ peak_pos,
                                              const float* __restrict__ topkv,
                                              const int* __restrict__ topkc,
                                              float* __restrict__ loss_bn) {
    __shared__ float qs[C];
    __shared__ float r1[256];
    __shared__ float r2[256];
    __shared__ float s_simsum, s_num;
    int bn = blockIdx.x;
    int b = bn / NC, n = bn % NC, t = threadIdx.x;
    if (peak_pos[bn] < 0) { if (t == 0) loss_bn[bn] = 0.0f; return; }
    if (t < C) qs[t] = qv[(size_t)bn * C + t];
    __syncthreads();
    float sim = 0.0f, kam = 0.0f, km = 0.0f;
    if (t < KALL) {
        const float* kr = k_all + ((size_t)b * KALL + t) * C;
        float dot = 0.0f;
        for (int c2 = 0; c2 < C; ++c2) dot += qs[c2] * kr[c2];
        sim = expf(dot / TAU);
        if (t < TOPK) {
            float posm = (topkv[b * TOPK + t] > 0.0f) ? 1.0f : 0.0f;
            kam = posm;
            km = (topkc[b * TOPK + t] == n) ? posm : 0.0f;
        } else {
            int j = t - TOPK;
            kam = (peak_pos[b * NC + j] >= 0) ? 1.0f : 0.0f;
            km = (j == n) ? 1.0f : 0.0f;  // class_mask[b,n]==1 here
        }
    }
    r1[t] = sim * kam;
    r2[t] = km;
    __syncthreads();
    for (int s = 128; s > 0; s >>= 1) {
        if (t < s) { r1[t] += r1[t + s]; r2[t] += r2[t + s]; }
        __syncthreads();
    }
    if (t == 0) {
        float ss = r1[0];
        s_simsum = (ss == 0.0f) ? 1.0f : ss;
        s_num = (r2[0] == 0.0f) ? 1.0f : r2[0];
    }
    __syncthreads();
    r1[t] = (km > 0.0f) ? logf(sim / s_simsum) : 0.0f;
    __syncthreads();
    for (int s = 128; s > 0; s >>= 1) {
        if (t < s) r1[t] += r1[t + s];
        __syncthreads();
    }
    if (t == 0) loss_bn[bn] = r1[0] / s_num;
}

// ---------------- fused: pseudo_hm scatter (blocks 0-7) + final loss (block 8) ----------------
// Ordered by kernel boundary only — no atomics, no fences.
__global__ void k_scatter_final(const float* __restrict__ topkv, const int* __restrict__ topki,
                                const int* __restrict__ topkc,
                                const float* __restrict__ loss_bn,
                                const int* __restrict__ peak_pos, float* out) {
    if (blockIdx.x < 8) {
        int i = blockIdx.x * 256 + threadIdx.x;    // 0..2047
        int b = i / TOPK;
        if (topkv[i] > 0.0f)
            out[1 + ((size_t)b * NC + topkc[i]) * HW + topki[i]] = 0.9f;
        return;
    }
    __shared__ float r1[256];
    __shared__ float r2[256];
    int t = threadIdx.x;
    float s = 0.0f, cnt = 0.0f;
    for (int i = t; i < BS * NC; i += 256) {
        s += loss_bn[i];
        cnt += (peak_pos[i] >= 0) ? 1.0f : 0.0f;
    }
    r1[t] = s; r2[t] = cnt;
    __syncthreads();
    for (int st = 128; st > 0; st >>= 1) {
        if (t < st) { r1[t] += r1[t + st]; r2[t] += r2[t + st]; }
        __syncthreads();
    }
    if (t == 0) out[0] = -(r1[0] / r2[0]);
}

extern "C" void kernel_launch(void* const* d_in, const int* in_sizes, int n_in,
                              void* d_out, int out_size, void* d_ws, size_t ws_size,
                              hipStream_t stream) {
    const float* feat  = (const float*)d_in[0];
    const float* score = (const float*)d_in[1];
    const float* hm    = (const float*)d_in[2];
    float* out = (float*)d_out;

    char* ws = (char*)d_ws;
    size_t off = 0;
    auto alloc = [&](size_t bytes) -> void* {
        void* p = ws + off;
        off += (bytes + 255) & ~(size_t)255;
        return p;
    };
    int*   peak_pos = (int*)  alloc((size_t)BS * NC * 4);
    float* maxv     = (float*)alloc((size_t)BS * HW * 4);
    int*   clsidx   = (int*)  alloc((size_t)BS * HW * 4);
    float* topkv    = (float*)alloc((size_t)BS * TOPK * 4);
    int*   topki    = (int*)  alloc((size_t)BS * TOPK * 4);
    int*   topkc    = (int*)  alloc((size_t)BS * TOPK * 4);
    float* k_all    = (float*)alloc((size_t)BS * KALL * C * 4);
    float* qv       = (float*)alloc((size_t)BS * NC * C * 4);
    float* loss_bn  = (float*)alloc((size_t)BS * NC * 4);

    k_peak_zero<<<BS * NC + ZBLK, 1024, 0, stream>>>(hm, peak_pos, out);
    dim3 gmax(HW / 4 / 256, BS);
    k_max<<<gmax, 256, 0, stream>>>(score, peak_pos, maxv, clsidx);
    k_topk<<<BS, 1024, 0, stream>>>(maxv, clsidx, topkv, topki, topkc);
    k_gather<<<BS * KALL, 64, 0, stream>>>(feat, peak_pos, topki, k_all, qv);
    k_loss<<<BS * NC, 256, 0, stream>>>(k_all, qv, peak_pos, topkv, topkc, loss_bn);
    k_scatter_final<<<9, 256, 0, stream>>>(topkv, topki, topkc, loss_bn, peak_pos, out);
}